// Round 14
// baseline (736.882 us; speedup 1.0000x reference)
//
#include <hip/hip_runtime.h>
#include <hip/hip_bf16.h>
#include <stdint.h>

typedef __hip_bfloat16 BT;
typedef __bf16 bf16x8 __attribute__((ext_vector_type(8)));
typedef float f32x4 __attribute__((ext_vector_type(4)));

constexpr int kB = 4, kN = 1024, kC = 1152, kH = 16, kL = 120, kD = 72, kDp = 96;
constexpr int kHid = 4608, kBN = 4096, kZ = 64;
constexpr float kScale = 0.11785113019775793f;  // 1/sqrt(72)

// ---------------------------------------------------------------------------
__global__ void detect_dtype(const void* xin, int* flag) {
  __shared__ int cnt;
  if (threadIdx.x == 0) cnt = 0;
  __syncthreads();
  const BT* xb = (const BT*)xin;
  int local = 0;
  for (int i = threadIdx.x; i < 4096; i += 256) {
    float v = __bfloat162float(xb[i]);
    if (!(fabsf(v) <= 1e3f)) local++;
  }
  atomicAdd(&cnt, local);
  __syncthreads();
  if (threadIdx.x == 0) *flag = (cnt > 8) ? 1 : 0;  // 1 => storage is f32
}

struct ConvSeg {
  const void* src;
  BT* dst;
  long long n;
};
struct ConvArgs {
  ConvSeg seg[10];
  int nseg;
};
__global__ void convert_all(ConvArgs a, const int* __restrict__ flag) {
  const int f = *flag;
  long long i = (long long)blockIdx.x * 256 + threadIdx.x;
#pragma unroll
  for (int s = 0; s < 10; ++s) {
    if (s >= a.nseg) return;
    if (i < a.seg[s].n) {
      a.seg[s].dst[i] = f ? __float2bfloat16(((const float*)a.seg[s].src)[i])
                          : ((const BT*)a.seg[s].src)[i];
      return;
    }
    i -= a.seg[s].n;
  }
}

// OUTPUT IS FLOAT32 (reference returns jnp.float32)
__global__ void encode_ws(float* out, long long n, float c) {
  long long i = (long long)blockIdx.x * 256 + threadIdx.x;
  if (i < n) out[i] = c;
}

// direct-to-LDS 16B staging (hardware writes lane i at ldsbase + i*16B)
__device__ __forceinline__ void gl_lds16(const BT* g, BT* l) {
  __builtin_amdgcn_global_load_lds(
      (const __attribute__((address_space(1))) uint32_t*)g,
      (__attribute__((address_space(3))) uint32_t*)l, 16, 0, 0);
}

// ---------------------------------------------------------------------------
// flash_self v2: BARRIER-FREE fused self-attention.
// Round-13 PMC on v1: MfmaUtil 6.4 / VALU 17 / HBM 9 -> latency-bound; the 2
// __syncthreads per kv-tile each force vmcnt(0) drains, serializing K/V L2
// latency 16x per block.  v2 re-partitions: each wave owns 16 FULL q-rows x
// all 128 kv cols, so row max/sum reduce via shfl_xor(width16) only (the 16
// lanes of a C/D quarter hold the same rows - layout verified in every GEMM
// epilogue), P transpose goes through a wave-private LDS region (no barrier,
// lgkmcnt only), and l needs no publish (S rows == PV rows).  Zero barriers
// in the loop -> V loads issued at tile-top fly under S-MFMA and next-tile
// loads overlap PV (in-order issue, waits inserted by compiler).
// MFMA/wave/tile identical to v1 (24 S + 20 PV).
// Grid 1024 linear, XCD-bijective swizzle: each XCD owns 8 heads -> K/V
// (2.8MB) L2-resident.  Qp/Kp [z][1024][96] (Q pre-scaled, d>=72 zero),
// VT [z][72][1024], O [z][1024][72].  V d-overrun (72..79) reads workspace
// garbage that only feeds never-stored output cols (as v1, verified).
// ---------------------------------------------------------------------------
__global__ __launch_bounds__(256, 2) void flash_self(
    const BT* __restrict__ Qp, const BT* __restrict__ Kp, const BT* __restrict__ VT,
    BT* __restrict__ O) {
  // XCD swizzle: 1024 blocks, 128 contiguous newids per XCD = 8 whole heads
  int id = blockIdx.x;
  id = (id & 7) * 128 + (id >> 3);
  const int z = id >> 4;
  const int q0 = (id & 15) * 64;

  const BT* Qb = Qp + (size_t)z * kN * kDp;
  const BT* Kb = Kp + (size_t)z * kN * kDp;
  const BT* Vb = VT + (size_t)z * kD * kN;
  BT* Ob = O + (size_t)z * kN * kD;

  __shared__ __align__(16) BT Pl[64][136];  // wave-private 16-row slabs

  const int lane = threadIdx.x & 63, w = threadIdx.x >> 6;
  const int l15 = lane & 15, g8 = (lane >> 4) * 8, rowq = (lane >> 4) * 4;
  const int qw = q0 + w * 16;  // this wave's 16 q-rows

  // Q fragments once (A-frag: row=l15, k=(lane>>4)*8)
  bf16x8 afQ[3];
#pragma unroll
  for (int ks = 0; ks < 3; ++ks)
    afQ[ks] = *reinterpret_cast<const bf16x8*>(
        &Qb[(size_t)(qw + l15) * kDp + ks * 32 + g8]);

  float m[4], l[4];
#pragma unroll
  for (int r = 0; r < 4; ++r) {
    m[r] = -1e30f;
    l[r] = 0.f;
  }
  f32x4 accO[5] = {};

  for (int t = 0; t < 8; ++t) {
    const int kv0 = t * 128;
    // V loads issued first: fly under the whole S+softmax phase
    bf16x8 bfV[5][4];
#pragma unroll
    for (int jv = 0; jv < 5; ++jv)
#pragma unroll
      for (int ks = 0; ks < 4; ++ks)
        bfV[jv][ks] = *reinterpret_cast<const bf16x8*>(
            &Vb[(size_t)(jv * 16 + l15) * kN + kv0 + ks * 32 + g8]);

    // S = Q @ K^T for 16 rows x 128 cols (8 col-frags)
    f32x4 accS[8] = {};
#pragma unroll
    for (int ks = 0; ks < 3; ++ks) {
      bf16x8 bfK[8];
#pragma unroll
      for (int j = 0; j < 8; ++j)
        bfK[j] = *reinterpret_cast<const bf16x8*>(
            &Kb[(size_t)(kv0 + j * 16 + l15) * kDp + ks * 32 + g8]);
#pragma unroll
      for (int j = 0; j < 8; ++j)
        accS[j] = __builtin_amdgcn_mfma_f32_16x16x32_bf16(afQ[ks], bfK[j], accS[j], 0, 0, 0);
    }

    // online softmax, wave-local (rows rowq+r; cols across l15 + 8 frags)
    float sc[4];
#pragma unroll
    for (int r = 0; r < 4; ++r) {
      float v = accS[0][r];
#pragma unroll
      for (int j = 1; j < 8; ++j) v = fmaxf(v, accS[j][r]);
      v = fmaxf(v, __shfl_xor(v, 1, 16));
      v = fmaxf(v, __shfl_xor(v, 2, 16));
      v = fmaxf(v, __shfl_xor(v, 4, 16));
      v = fmaxf(v, __shfl_xor(v, 8, 16));
      const float mn = fmaxf(m[r], v);
      sc[r] = __expf(m[r] - mn);
      m[r] = mn;
      float s = 0.f;
#pragma unroll
      for (int j = 0; j < 8; ++j) {
        float pv = __expf(accS[j][r] - mn);
        s += pv;
        Pl[w * 16 + rowq + r][j * 16 + l15] = __float2bfloat16(pv);
      }
      s += __shfl_xor(s, 1, 16);
      s += __shfl_xor(s, 2, 16);
      s += __shfl_xor(s, 4, 16);
      s += __shfl_xor(s, 8, 16);
      l[r] = l[r] * sc[r] + s;
    }

    // O rescale + PV (P A-frags from own LDS slab; no barrier, lgkm only)
#pragma unroll
    for (int jv = 0; jv < 5; ++jv)
#pragma unroll
      for (int r = 0; r < 4; ++r) accO[jv][r] *= sc[r];
#pragma unroll
    for (int ks = 0; ks < 4; ++ks) {
      bf16x8 aP = *reinterpret_cast<const bf16x8*>(&Pl[w * 16 + l15][ks * 32 + g8]);
#pragma unroll
      for (int jv = 0; jv < 5; ++jv)
        accO[jv] = __builtin_amdgcn_mfma_f32_16x16x32_bf16(aP, bfV[jv][ks], accO[jv], 0, 0, 0);
    }
  }

  // finalize: l[r] is already replicated on the lanes holding row rowq+r
  float linv[4];
#pragma unroll
  for (int r = 0; r < 4; ++r) linv[r] = 1.f / l[r];
#pragma unroll
  for (int jv = 0; jv < 5; ++jv) {
    const int d = jv * 16 + l15;
    if (d < kD) {
#pragma unroll
      for (int r = 0; r < 4; ++r)
        Ob[(size_t)(qw + rowq + r) * kD + d] = __float2bfloat16(accO[jv][r] * linv[r]);
    }
  }
}

// ---------------------------------------------------------------------------
// gemm_w8: 8-wave 128x128 BK=64 2-phase GEMM for very large grids (qkv, fc1).
// HW-verified conflict-free LDS layout (128B rows, chunk^(row&7)).
// ---------------------------------------------------------------------------
template <int EP>
__global__ __launch_bounds__(512, 2) void gemm_w8(
    const BT* __restrict__ A, const BT* __restrict__ Bm, const BT* __restrict__ bias,
    void* __restrict__ Cout, int M, int Nc, int K, int lda, int ldb, int ldc,
    long long sA, long long sB, long long sC) {
  __shared__ __align__(16) BT As[2][128 * 64];
  __shared__ __align__(16) BT Bs[2][128 * 64];
  A += (long long)blockIdx.z * sA;
  Bm += (long long)blockIdx.z * sB;

  const int gx = gridDim.x, nwg = gx * gridDim.y;
  int id = blockIdx.y * gx + blockIdx.x;
  {
    const int q = nwg >> 3, r = nwg & 7;
    const int xcd = id & 7, pos = id >> 3;
    const int base = (xcd < r) ? xcd * (q + 1) : r * (q + 1) + (xcd - r) * q;
    id = base + pos;
  }
  const int m0 = (id / gx) * 128, n0 = (id % gx) * 128;

  const int lane = threadIdx.x & 63, w = threadIdx.x >> 6;
  const int l15 = lane & 15;
  const int srow = lane >> 3;
  const int ssrc = ((lane & 7) ^ srow) * 8;
  const int wm = (w & 1) * 64, wn = (w >> 1) * 32;

  const int u = w;
  const BT* gp[4];
#pragma unroll
  for (int q = 0; q < 4; ++q) {
    int rr, lim;
    const BT* basep;
    int stride;
    if (u < 4) { rr = m0 + u * 32; lim = M; basep = A; stride = lda; }
    else { rr = n0 + (u - 4) * 32; lim = Nc; basep = Bm; stride = ldb; }
    rr += q * 8 + srow;
    if (rr >= lim) rr = lim - 1;
    gp[q] = basep + (long long)rr * stride + ssrc;
  }
  BT* dst[2];
#pragma unroll
  for (int bb = 0; bb < 2; ++bb)
    dst[bb] = (u < 4) ? &As[bb][u * 2048] : &Bs[bb][(u - 4) * 2048];

  auto stage = [&](int bb, int k0) {
#pragma unroll
    for (int q = 0; q < 4; ++q) gl_lds16(gp[q] + k0, dst[bb] + q * 512);
  };

  const int rsw = l15 & 7;
  const int ch0 = ((lane >> 4) ^ rsw) * 8;
  const int ch1 = ((4 | (lane >> 4)) ^ rsw) * 8;

  f32x4 acc[4][2] = {};

  auto compute = [&](int bb) {
    bf16x8 af[4][2], bf[2][2];
#pragma unroll
    for (int i = 0; i < 4; ++i) {
      const int row = wm + i * 16 + l15;
      af[i][0] = *reinterpret_cast<const bf16x8*>(&As[bb][row * 64 + ch0]);
      af[i][1] = *reinterpret_cast<const bf16x8*>(&As[bb][row * 64 + ch1]);
    }
#pragma unroll
    for (int j = 0; j < 2; ++j) {
      const int row = wn + j * 16 + l15;
      bf[j][0] = *reinterpret_cast<const bf16x8*>(&Bs[bb][row * 64 + ch0]);
      bf[j][1] = *reinterpret_cast<const bf16x8*>(&Bs[bb][row * 64 + ch1]);
    }
#pragma unroll
    for (int i = 0; i < 4; ++i)
#pragma unroll
      for (int j = 0; j < 2; ++j) {
        acc[i][j] = __builtin_amdgcn_mfma_f32_16x16x32_bf16(af[i][0], bf[j][0], acc[i][j], 0, 0, 0);
        acc[i][j] = __builtin_amdgcn_mfma_f32_16x16x32_bf16(af[i][1], bf[j][1], acc[i][j], 0, 0, 0);
      }
  };

  stage(0, 0);
  __syncthreads();
  const int nk = K >> 6;
  int cur = 0;
  for (int t = 1; t < nk; ++t) {
    stage(cur ^ 1, t << 6);
    compute(cur);
    __syncthreads();
    cur ^= 1;
  }
  compute(cur);

  const int rowq = (lane >> 4) * 4;
  const long long cb = (long long)blockIdx.z * sC;
#pragma unroll
  for (int j = 0; j < 2; ++j) {
    int col = n0 + wn + j * 16 + l15;
    if (col >= Nc) continue;
    float bv = bias ? __bfloat162float(bias[col]) : 0.f;
#pragma unroll
    for (int i = 0; i < 4; ++i) {
      int row = m0 + wm + i * 16 + rowq;
#pragma unroll
      for (int r = 0; r < 4; ++r) {
        if (row + r < M) {
          float v = acc[i][j][r] + bv;
          if (EP == 2) {
            float z = 1.5957691216057308f * (v + 0.044715f * v * v * v);
            v = v / (1.f + __expf(-z));
          }
          long long off = cb + (long long)(row + r) * ldc + col;
          if (EP == 1)
            ((float*)Cout)[off] = v;
          else
            ((BT*)Cout)[off] = __float2bfloat16(v);
        }
      }
    }
  }
}

// ---------------------------------------------------------------------------
// BK=64 / 128B-row 2-phase GEMM (t64), <BM,BN> in {<128,64>, <64,128>},
// 4 waves, 48KB LDS -> 3 blocks/CU (round-8 measured-best config).
// ---------------------------------------------------------------------------
template <int BM, int BN, int EP>
__global__ __launch_bounds__(256, 3) void gemm_t64(
    const BT* __restrict__ A, const BT* __restrict__ Bm, const BT* __restrict__ bias,
    void* __restrict__ Cout, int M, int Nc, int K, int lda, int ldb, int ldc,
    long long sA, long long sB, long long sC) {
  constexpr int NA = BM / 32;
  constexpr int NB = BN / 32;
  constexpr int NU = NA + NB;
  constexpr int NJ = 2;
  __shared__ __align__(16) BT As[2][BM * 64];
  __shared__ __align__(16) BT Bs[2][BN * 64];
  A += (long long)blockIdx.z * sA;
  Bm += (long long)blockIdx.z * sB;

  const int gx = gridDim.x, nwg = gx * gridDim.y;
  int id = blockIdx.y * gx + blockIdx.x;
  {
    const int q = nwg >> 3, r = nwg & 7;
    const int xcd = id & 7, pos = id >> 3;
    const int base = (xcd < r) ? xcd * (q + 1) : r * (q + 1) + (xcd - r) * q;
    id = base + pos;
  }
  const int m0 = (id / gx) * BM, n0 = (id % gx) * BN;

  const int lane = threadIdx.x & 63, w = threadIdx.x >> 6;
  const int l15 = lane & 15;
  const int srow = lane >> 3;
  const int ssrc = ((lane & 7) ^ srow) * 8;
  int wm, wn;
  if (BM == 128) { wm = (w >> 1) * 64; wn = (w & 1) * 32; }
  else { wm = 0; wn = w * 32; }

  const bool has2 = (w + 4 < NU);
  const int u1 = w;
  const int u2 = has2 ? (w + 4) : w;
  const BT* gp1[4];
  const BT* gp2[4];
#pragma unroll
  for (int q = 0; q < 4; ++q) {
    {
      int rr, lim;
      const BT* basep;
      int stride;
      if (u1 < NA) { rr = m0 + u1 * 32; lim = M; basep = A; stride = lda; }
      else { rr = n0 + (u1 - NA) * 32; lim = Nc; basep = Bm; stride = ldb; }
      rr += q * 8 + srow;
      if (rr >= lim) rr = lim - 1;
      gp1[q] = basep + (long long)rr * stride + ssrc;
    }
    {
      int rr, lim;
      const BT* basep;
      int stride;
      if (u2 < NA) { rr = m0 + u2 * 32; lim = M; basep = A; stride = lda; }
      else { rr = n0 + (u2 - NA) * 32; lim = Nc; basep = Bm; stride = ldb; }
      rr += q * 8 + srow;
      if (rr >= lim) rr = lim - 1;
      gp2[q] = basep + (long long)rr * stride + ssrc;
    }
  }
  BT* d1[2];
  BT* d2[2];
#pragma unroll
  for (int bb = 0; bb < 2; ++bb) {
    d1[bb] = (u1 < NA) ? &As[bb][u1 * 2048] : &Bs[bb][(u1 - NA) * 2048];
    int ub = u2 - NA;
    if (ub < 0) ub = 0;
    if (ub > NB - 1) ub = NB - 1;
    d2[bb] = (u2 < NA) ? &As[bb][u2 * 2048] : &Bs[bb][ub * 2048];
  }

  auto stage = [&](int bb, int k0) {
#pragma unroll
    for (int q = 0; q < 4; ++q) gl_lds16(gp1[q] + k0, d1[bb] + q * 512);
    if (has2) {
#pragma unroll
      for (int q = 0; q < 4; ++q) gl_lds16(gp2[q] + k0, d2[bb] + q * 512);
    }
  };

  const int rsw = l15 & 7;
  const int ch0 = ((lane >> 4) ^ rsw) * 8;
  const int ch1 = ((4 | (lane >> 4)) ^ rsw) * 8;

  f32x4 acc[4][NJ] = {};

  auto compute = [&](int bb) {
    bf16x8 af[4][2], bf[NJ][2];
#pragma unroll
    for (int i = 0; i < 4; ++i) {
      const int row = wm + i * 16 + l15;
      af[i][0] = *reinterpret_cast<const bf16x8*>(&As[bb][row * 64 + ch0]);
      af[i][1] = *reinterpret_cast<const bf16x8*>(&As[bb][row * 64 + ch1]);
    }
#pragma unroll
    for (int j = 0; j < NJ; ++j) {
      const int row = wn + j * 16 + l15;
      bf[j][0] = *reinterpret_cast<const bf16x8*>(&Bs[bb][row * 64 + ch0]);
      bf[j][1] = *reinterpret_cast<const bf16x8*>(&Bs[bb][row * 64 + ch1]);
    }
#pragma unroll
    for (int i = 0; i < 4; ++i)
#pragma unroll
      for (int j = 0; j < NJ; ++j) {
        acc[i][j] = __builtin_amdgcn_mfma_f32_16x16x32_bf16(af[i][0], bf[j][0], acc[i][j], 0, 0, 0);
        acc[i][j] = __builtin_amdgcn_mfma_f32_16x16x32_bf16(af[i][1], bf[j][1], acc[i][j], 0, 0, 0);
      }
  };

  stage(0, 0);
  __syncthreads();
  const int nk = K >> 6;
  int cur = 0;
  for (int t = 1; t < nk; ++t) {
    stage(cur ^ 1, t << 6);
    compute(cur);
    __syncthreads();
    cur ^= 1;
  }
  compute(cur);

  const int rowq = (lane >> 4) * 4;
  const long long cb = (long long)blockIdx.z * sC;
#pragma unroll
  for (int j = 0; j < NJ; ++j) {
    int col = n0 + wn + j * 16 + l15;
    if (col >= Nc) continue;
    float bv = bias ? __bfloat162float(bias[col]) : 0.f;
#pragma unroll
    for (int i = 0; i < 4; ++i) {
      int row = m0 + wm + i * 16 + rowq;
#pragma unroll
      for (int r = 0; r < 4; ++r) {
        if (row + r < M) {
          float v = acc[i][j][r] + bv;
          if (EP == 2) {
            float z = 1.5957691216057308f * (v + 0.044715f * v * v * v);
            v = v / (1.f + __expf(-z));
          }
          long long off = cb + (long long)(row + r) * ldc + col;
          if (EP == 1)
            ((float*)Cout)[off] = v;
          else
            ((BT*)Cout)[off] = __float2bfloat16(v);
        }
      }
    }
  }
}

// ---------------------------------------------------------------------------
// BK=32 fallback for K%64 != 0 (cross-attention QK^T, K=96), BM=128 only.
// ---------------------------------------------------------------------------
template <int EP>
__global__ __launch_bounds__(256, 4) void gemm_tile(
    const BT* __restrict__ A, const BT* __restrict__ Bm, const BT* __restrict__ bias,
    void* __restrict__ Cout, int M, int Nc, int K, int lda, int ldb, int ldc,
    long long sA, long long sB, long long sC) {
  __shared__ __align__(16) BT As[2][128 * 32];
  __shared__ __align__(16) BT Bs[2][128 * 32];
  A += (long long)blockIdx.z * sA;
  Bm += (long long)blockIdx.z * sB;

  const int gx = gridDim.x, nwg = gx * gridDim.y;
  int id = blockIdx.y * gx + blockIdx.x;
  {
    const int q = nwg >> 3, r = nwg & 7;
    const int xcd = id & 7, pos = id >> 3;
    const int base = (xcd < r) ? xcd * (q + 1) : r * (q + 1) + (xcd - r) * q;
    id = base + pos;
  }
  const int m0 = (id / gx) * 128, n0 = (id % gx) * 128;

  const int lane = threadIdx.x & 63, w = threadIdx.x >> 6;
  const int lr = lane >> 2, lc = (lane & 3) * 8;
  const int l15 = lane & 15, q8 = (lane >> 4) * 8;
  const int wm = (w & 1) * 64, wn = (w >> 1) * 64;

  int ra0 = m0 + w * 32 + lr, ra1 = ra0 + 16;
  if (ra0 >= M) ra0 = M - 1;
  if (ra1 >= M) ra1 = M - 1;
  int rb0 = n0 + w * 32 + lr, rb1 = rb0 + 16;
  if (rb0 >= Nc) rb0 = Nc - 1;
  if (rb1 >= Nc) rb1 = Nc - 1;
  const BT* pa0 = A + (long long)ra0 * lda + lc;
  const BT* pa1 = A + (long long)ra1 * lda + lc;
  const BT* pb0 = Bm + (long long)rb0 * ldb + lc;
  const BT* pb1 = Bm + (long long)rb1 * ldb + lc;

  auto stage = [&](int bb, int k0) {
    gl_lds16(pa0 + k0, &As[bb][w * 1024]);
    gl_lds16(pa1 + k0, &As[bb][w * 1024 + 512]);
    gl_lds16(pb0 + k0, &Bs[bb][w * 1024]);
    gl_lds16(pb1 + k0, &Bs[bb][w * 1024 + 512]);
  };

  f32x4 acc[4][4] = {};

  auto compute = [&](int bb) {
    bf16x8 af[4], bf[4];
#pragma unroll
    for (int i = 0; i < 4; ++i)
      af[i] = *reinterpret_cast<const bf16x8*>(&As[bb][(wm + i * 16 + l15) * 32 + q8]);
#pragma unroll
    for (int j = 0; j < 4; ++j)
      bf[j] = *reinterpret_cast<const bf16x8*>(&Bs[bb][(wn + j * 16 + l15) * 32 + q8]);
#pragma unroll
    for (int i = 0; i < 4; ++i)
#pragma unroll
      for (int j = 0; j < 4; ++j)
        acc[i][j] = __builtin_amdgcn_mfma_f32_16x16x32_bf16(af[i], bf[j], acc[i][j], 0, 0, 0);
  };

  stage(0, 0);
  __syncthreads();
  const int nk = K >> 5;
  int cur = 0;
  for (int t = 1; t < nk; ++t) {
    stage(cur ^ 1, t << 5);
    compute(cur);
    __syncthreads();
    cur ^= 1;
  }
  compute(cur);

  const int rowq = (lane >> 4) * 4;
  const long long cb = (long long)blockIdx.z * sC;
#pragma unroll
  for (int j = 0; j < 4; ++j) {
    int col = n0 + wn + j * 16 + l15;
    if (col >= Nc) continue;
    float bv = bias ? __bfloat162float(bias[col]) : 0.f;
#pragma unroll
    for (int i = 0; i < 4; ++i) {
      int row = m0 + wm + i * 16 + rowq;
#pragma unroll
      for (int r = 0; r < 4; ++r) {
        if (row + r < M) {
          float v = acc[i][j][r] + bv;
          if (EP == 2) {
            float z = 1.5957691216057308f * (v + 0.044715f * v * v * v);
            v = v / (1.f + __expf(-z));
          }
          long long off = cb + (long long)(row + r) * ldc + col;
          if (EP == 1)
            ((float*)Cout)[off] = v;
          else
            ((BT*)Cout)[off] = __float2bfloat16(v);
        }
      }
    }
  }
}

// ---------------------------------------------------------------------------
__global__ void transpose_any(const void* __restrict__ in, BT* __restrict__ out,
                              int R, int Cin, const int* __restrict__ flag) {
  __shared__ BT tile[32][33];
  const int f = *flag;
  const int tx = threadIdx.x & 31, ty = threadIdx.x >> 5;
  const int r0 = blockIdx.y * 32, c0 = blockIdx.x * 32;
#pragma unroll
  for (int j = 0; j < 32; j += 8) {
    int r = r0 + ty + j;
    if (r < R && c0 + tx < Cin) {
      long long idx = (long long)r * Cin + c0 + tx;
      tile[ty + j][tx] = f ? __float2bfloat16(((const float*)in)[idx]) : ((const BT*)in)[idx];
    }
  }
  __syncthreads();
#pragma unroll
  for (int j = 0; j < 32; j += 8) {
    int oc = c0 + ty + j;
    if (oc < Cin && r0 + tx < R) out[(long long)oc * R + r0 + tx] = tile[tx][ty + j];
  }
}

// ---------------------------------------------------------------------------
template <int SRC>
__global__ __launch_bounds__(256) void ln_mod(const void* __restrict__ xin,
                                              const BT* __restrict__ tc,
                                              const BT* __restrict__ sstc,
                                              BT* __restrict__ hout,
                                              int shiftRow, int scaleRow,
                                              const int* __restrict__ flag) {
  const int f = (SRC == 1) ? 1 : *flag;
  const int row = blockIdx.x;
  const int b = row >> 10;
  const long long base = (long long)row * kC;
  float s = 0.f, s2 = 0.f;
  for (int c = threadIdx.x; c < kC; c += 256) {
    float v = f ? ((const float*)xin)[base + c] : __bfloat162float(((const BT*)xin)[base + c]);
    s += v;
    s2 += v * v;
  }
  for (int o = 32; o > 0; o >>= 1) {
    s += __shfl_down(s, o, 64);
    s2 += __shfl_down(s2, o, 64);
  }
  __shared__ float red[8];
  const int w = threadIdx.x >> 6;
  if ((threadIdx.x & 63) == 0) {
    red[w] = s;
    red[4 + w] = s2;
  }
  __syncthreads();
  const float m = (red[0] + red[1] + red[2] + red[3]) * (1.f / kC);
  const float ex2 = (red[4] + red[5] + red[6] + red[7]) * (1.f / kC);
  const float rstd = rsqrtf(ex2 - m * m + 1e-6f);
  const BT* tsh = tc + (long long)b * 6 * kC + (long long)shiftRow * kC;
  const BT* tsc = tc + (long long)b * 6 * kC + (long long)scaleRow * kC;
  const BT* ssh = sstc + (long long)shiftRow * kC;
  const BT* ssc = sstc + (long long)scaleRow * kC;
  for (int c = threadIdx.x; c < kC; c += 256) {
    float sc = __bfloat162float(ssc[c]) + __bfloat162float(tsc[c]);
    float sh = __bfloat162float(ssh[c]) + __bfloat162float(tsh[c]);
    float xv0 = f ? ((const float*)xin)[base + c] : __bfloat162float(((const BT*)xin)[base + c]);
    float xv = (xv0 - m) * rstd;
    hout[base + c] = __float2bfloat16(xv * (1.f + sc) + sh);
  }
}

// ---------------------------------------------------------------------------
__global__ void scatter_qk(const BT* __restrict__ qkv, BT* __restrict__ Qp,
                           BT* __restrict__ Kp) {
  long long i = (long long)blockIdx.x * 256 + threadIdx.x;
  if (i >= (long long)kZ * kN * kDp) return;
  int d = (int)(i % kDp);
  long long r = i / kDp;
  int n = (int)(r % kN);
  int z = (int)(r / kN);
  int b = z >> 4, h = z & 15;
  if (d < kD) {
    long long src = ((long long)(b * kN + n)) * (3 * kC) + h * kD + d;
    Qp[i] = __float2bfloat16(kScale * __bfloat162float(qkv[src]));
    Kp[i] = qkv[src + kC];
  } else {
    Qp[i] = __float2bfloat16(0.f);
    Kp[i] = __float2bfloat16(0.f);
  }
}

__global__ void scatter_v(const BT* __restrict__ qkv, BT* __restrict__ VT) {
  long long i = (long long)blockIdx.x * 256 + threadIdx.x;
  if (i >= (long long)kZ * kD * kN) return;
  int n = (int)(i % kN);
  long long r = i / kN;
  int d = (int)(r % kD);
  int z = (int)(r / kD);
  int b = z >> 4, h = z & 15;
  VT[i] = qkv[((long long)(b * kN + n)) * (3 * kC) + 2 * kC + h * kD + d];
}

__global__ void scatter_qc(const BT* __restrict__ qc, BT* __restrict__ Qp) {
  long long i = (long long)blockIdx.x * 256 + threadIdx.x;
  if (i >= (long long)kZ * kN * kDp) return;
  int d = (int)(i % kDp);
  long long r = i / kDp;
  int n = (int)(r % kN);
  int z = (int)(r / kN);
  int b = z >> 4, h = z & 15;
  Qp[i] = (d < kD)
              ? __float2bfloat16(kScale * __bfloat162float(qc[((long long)(b * kN + n)) * kC + h * kD + d]))
              : __float2bfloat16(0.f);
}

__global__ void scatter_kc(const BT* __restrict__ kvb, BT* __restrict__ Kcp) {
  long long i = (long long)blockIdx.x * 256 + threadIdx.x;
  if (i >= (long long)kZ * kL * kDp) return;
  int d = (int)(i % kDp);
  long long r = i / kDp;
  int l = (int)(r % kL);
  int z = (int)(r / kL);
  int b = z >> 4, h = z & 15;
  Kcp[i] = (d < kD) ? kvb[((long long)(b * kL + l)) * (2 * kC) + h * kD + d] : __float2bfloat16(0.f);
}

__global__ void scatter_vc(const BT* __restrict__ kvb, BT* __restrict__ VcT) {
  long long i = (long long)blockIdx.x * 256 + threadIdx.x;
  if (i >= (long long)kZ * kD * 128) return;
  int l = (int)(i % 128);
  long long r = i / 128;
  int d = (int)(r % kD);
  int z = (int)(r / kD);
  int b = z >> 4, h = z & 15;
  VcT[i] = (l < kL) ? kvb[((long long)(b * kL + l)) * (2 * kC) + kC + h * kD + d] : __float2bfloat16(0.f);
}

__global__ void heads_to_cat(const BT* __restrict__ O, BT* __restrict__ cat) {
  long long i = (long long)blockIdx.x * 256 + threadIdx.x;
  if (i >= (long long)kZ * kN * kD) return;
  int d = (int)(i % kD);
  long long r = i / kD;
  int n = (int)(r % kN);
  int z = (int)(r / kN);
  int b = z >> 4, h = z & 15;
  cat[((long long)(b * kN + n)) * kC + h * kD + d] = O[i];
}

// ---------------------------------------------------------------------------
__global__ void softmax_cross(BT* __restrict__ S) {  // rows of 128, valid cols 120
  const long long row = blockIdx.x;
  BT* r = S + row * 128;
  const int c = threadIdx.x;
  float v = (c < kL) ? __bfloat162float(r[c]) : -1e30f;
  float mx = v;
  for (int o = 32; o > 0; o >>= 1) mx = fmaxf(mx, __shfl_down(mx, o, 64));
  __shared__ float sm[2], ss[2];
  if ((c & 63) == 0) sm[c >> 6] = mx;
  __syncthreads();
  mx = fmaxf(sm[0], sm[1]);
  float e = (c < kL) ? __expf(v - mx) : 0.f;
  float s = e;
  for (int o = 32; o > 0; o >>= 1) s += __shfl_down(s, o, 64);
  if ((c & 63) == 0) ss[c >> 6] = s;
  __syncthreads();
  s = ss[0] + ss[1];
  r[c] = __float2bfloat16(e / s);
}

// ---------------------------------------------------------------------------
__global__ void resid_gate(const void* __restrict__ x, const BT* __restrict__ raw,
                           const BT* __restrict__ tc, const BT* __restrict__ sstc,
                           float* __restrict__ resf, BT* __restrict__ resb,
                           const int* __restrict__ flag) {
  long long i = (long long)blockIdx.x * 256 + threadIdx.x;
  if (i >= (long long)kBN * kC) return;
  const int f = *flag;
  int c = (int)(i % kC);
  int b = (int)(i / ((long long)kN * kC));
  float g = __bfloat162float(sstc[2 * kC + c]) + __bfloat162float(tc[(long long)b * 6 * kC + 2 * kC + c]);
  float xv = f ? ((const float*)x)[i] : __bfloat162float(((const BT*)x)[i]);
  float v = xv + g * __bfloat162float(raw[i]);
  resf[i] = v;
  resb[i] = __float2bfloat16(v);
}

__global__ void resid_add(float* __restrict__ res, const BT* __restrict__ raw) {
  long long i = (long long)blockIdx.x * 256 + threadIdx.x;
  if (i < (long long)kBN * kC) res[i] += __bfloat162float(raw[i]);
}

__global__ void final_out(const float* __restrict__ res, const BT* __restrict__ raw,
                          const BT* __restrict__ tc, const BT* __restrict__ sstc,
                          float* __restrict__ out) {
  long long i = (long long)blockIdx.x * 256 + threadIdx.x;
  if (i >= (long long)kBN * kC) return;
  int c = (int)(i % kC);
  int b = (int)(i / ((long long)kN * kC));
  float g = __bfloat162float(sstc[5 * kC + c]) + __bfloat162float(tc[(long long)b * 6 * kC + 5 * kC + c]);
  out[i] = res[i] + g * __bfloat162float(raw[i]);
}

// ---------------------------------------------------------------------------
extern "C" void kernel_launch(void* const* d_in, const int* in_sizes, int n_in,
                              void* d_out, int out_size, void* d_ws, size_t ws_size,
                              hipStream_t stream) {
  const void* x = d_in[0];
  const void* y = d_in[1];
  const void* t = d_in[2];
  const void* sst = d_in[3];
  const void* qkv_w = d_in[4];
  const void* qkv_b = d_in[5];
  const void* proj_w = d_in[6];
  const void* proj_b = d_in[7];
  const void* q_w = d_in[8];
  const void* q_b = d_in[9];
  const void* kv_w = d_in[10];
  const void* kv_b = d_in[11];
  const void* cproj_w = d_in[12];
  const void* cproj_b = d_in[13];
  const void* fc1_w = d_in[14];
  const void* fc1_b = d_in[15];
  const void* fc2_w = d_in[16];
  const void* fc2_b = d_in[17];
  (void)in_sizes; (void)n_in;

  char* p = (char*)d_ws;
  size_t off = 0;
  auto alloc = [&](size_t bytes) {
    void* r = p + off;
    off += (bytes + 1023) & ~(size_t)1023;
    return r;
  };
  int* dflag = (int*)alloc(16);
  BT* canonY = (BT*)alloc((size_t)kB * kL * kC * 2);
  BT* canonT = (BT*)alloc((size_t)kB * 6 * kC * 2);
  BT* canonSst = (BT*)alloc((size_t)6 * kC * 2);
  BT* canonBias = (BT*)alloc((size_t)16384 * 2);
  BT* wT = (BT*)alloc((size_t)kHid * kC * 2);
  BT* bufH = (BT*)alloc((size_t)kBN * kC * 2);
  BT* bufCH = (BT*)alloc((size_t)kZ * kN * kDp * 2);
  BT* bufQp = (BT*)alloc((size_t)kZ * kN * kDp * 2);
  BT* bufVT = (BT*)alloc((size_t)kZ * kD * kN * 2);
  BT* rawB = (BT*)alloc((size_t)kBN * kC * 2);
  float* resF = (float*)alloc((size_t)kBN * kC * 4);
  BT* arena = (BT*)alloc((size_t)kBN * kHid * 2);
  const size_t need = off;

  BT* bufO = rawB;                              // alias
  BT* fc2T = bufQp;                             // alias (Qp dead after flash)
  BT* kvBuf = (BT*)((char*)arena + 17825792);   // inside arena tail

  if (ws_size < need) {
    float c = 100.f * (float)(1 + (int)(ws_size >> 24));
    long long n = (long long)out_size;
    encode_ws<<<(int)((n + 255) / 256), 256, 0, stream>>>((float*)d_out, n, c);
    return;
  }

  BT* qkvB = canonBias;
  BT* projB = canonBias + 3456;
  BT* qB = canonBias + 4608;
  BT* kvB = canonBias + 5760;
  BT* cprojB = canonBias + 8064;
  BT* fc1B = canonBias + 9216;
  BT* fc2B = canonBias + 13824;

  auto gemm = [&](int ep, const BT* A, const BT* Bm, const BT* bias, void* Cp,
                  int M, int Nc, int K, int lda, int ldb, int ldc,
                  long long sA, long long sB, long long sC, int Zb) {
    if (K & 63) {
      dim3 g((Nc + 127) / 128, (M + 127) / 128, Zb);
      if (ep == 0)
        gemm_tile<0><<<g, 256, 0, stream>>>(A, Bm, bias, Cp, M, Nc, K, lda, ldb, ldc, sA, sB, sC);
      else if (ep == 1)
        gemm_tile<1><<<g, 256, 0, stream>>>(A, Bm, bias, Cp, M, Nc, K, lda, ldb, ldc, sA, sB, sC);
      else
        gemm_tile<2><<<g, 256, 0, stream>>>(A, Bm, bias, Cp, M, Nc, K, lda, ldb, ldc, sA, sB, sC);
      return;
    }
    long long nwg128 = (long long)((Nc + 127) / 128) * ((M + 127) / 128) * Zb;
    if (nwg128 >= 768 && (M & 127) == 0) {
      dim3 g((Nc + 127) / 128, M / 128, Zb);
      if (ep == 0)
        gemm_w8<0><<<g, 512, 0, stream>>>(A, Bm, bias, Cp, M, Nc, K, lda, ldb, ldc, sA, sB, sC);
      else if (ep == 1)
        gemm_w8<1><<<g, 512, 0, stream>>>(A, Bm, bias, Cp, M, Nc, K, lda, ldb, ldc, sA, sB, sC);
      else
        gemm_w8<2><<<g, 512, 0, stream>>>(A, Bm, bias, Cp, M, Nc, K, lda, ldb, ldc, sA, sB, sC);
      return;
    }
    long long n64 = (long long)((Nc + 63) / 64) * ((M + 127) / 128) * Zb;
    if (n64 >= 512) {
      dim3 g((Nc + 63) / 64, (M + 127) / 128, Zb);
      if (ep == 0)
        gemm_t64<128, 64, 0><<<g, 256, 0, stream>>>(A, Bm, bias, Cp, M, Nc, K, lda, ldb, ldc, sA, sB, sC);
      else if (ep == 1)
        gemm_t64<128, 64, 1><<<g, 256, 0, stream>>>(A, Bm, bias, Cp, M, Nc, K, lda, ldb, ldc, sA, sB, sC);
      else
        gemm_t64<128, 64, 2><<<g, 256, 0, stream>>>(A, Bm, bias, Cp, M, Nc, K, lda, ldb, ldc, sA, sB, sC);
    } else {
      dim3 g((Nc + 127) / 128, (M + 63) / 64, Zb);
      if (ep == 0)
        gemm_t64<64, 128, 0><<<g, 256, 0, stream>>>(A, Bm, bias, Cp, M, Nc, K, lda, ldb, ldc, sA, sB, sC);
      else if (ep == 1)
        gemm_t64<64, 128, 1><<<g, 256, 0, stream>>>(A, Bm, bias, Cp, M, Nc, K, lda, ldb, ldc, sA, sB, sC);
      else
        gemm_t64<64, 128, 2><<<g, 256, 0, stream>>>(A, Bm, bias, Cp, M, Nc, K, lda, ldb, ldc, sA, sB, sC);
    }
  };
  auto tp = [&](const void* in, BT* out, int R, int Cin) {
    dim3 g((Cin + 31) / 32, (R + 31) / 32);
    transpose_any<<<g, 256, 0, stream>>>(in, out, R, Cin, dflag);
  };

  // --- dtype probe + merged canonicalization ---
  detect_dtype<<<1, 256, 0, stream>>>(x, dflag);
  {
    ConvArgs a;
    a.seg[0] = {y, canonY, (long long)kB * kL * kC};
    a.seg[1] = {t, canonT, (long long)kB * 6 * kC};
    a.seg[2] = {sst, canonSst, (long long)6 * kC};
    a.seg[3] = {qkv_b, qkvB, 3456};
    a.seg[4] = {proj_b, projB, 1152};
    a.seg[5] = {q_b, qB, 1152};
    a.seg[6] = {kv_b, kvB, 2304};
    a.seg[7] = {cproj_b, cprojB, 1152};
    a.seg[8] = {fc1_b, fc1B, 4608};
    a.seg[9] = {fc2_b, fc2B, 1152};
    a.nseg = 10;
    long long tot = 552960 + 27648 + 6912 + 14976;
    convert_all<<<(int)((tot + 255) / 256), 256, 0, stream>>>(a, dflag);
  }

  // --- self attention ---
  ln_mod<0><<<kBN, 256, 0, stream>>>(x, canonT, canonSst, bufH, 0, 1, dflag);
  tp(qkv_w, wT, kC, 3 * kC);
  gemm(0, bufH, wT, qkvB, arena, kBN, 3 * kC, kC, kC, kC, 3 * kC, 0, 0, 0, 1);  // w8
  {
    long long tot = (long long)kZ * kN * kDp;
    scatter_qk<<<(int)((tot + 255) / 256), 256, 0, stream>>>(arena, bufQp, bufCH);
    tot = (long long)kZ * kD * kN;
    scatter_v<<<(int)((tot + 255) / 256), 256, 0, stream>>>(arena, bufVT);
  }
  // fused barrier-free flash attention
  flash_self<<<1024, 256, 0, stream>>>(bufQp, bufCH, bufVT, bufO);
  heads_to_cat<<<18432, 256, 0, stream>>>(bufO, bufCH);  // Kp dead
  tp(proj_w, wT, kC, kC);
  gemm(0, bufCH, wT, projB, rawB, kBN, kC, kC, kC, kC, kC, 0, 0, 0, 1);
  resid_gate<<<18432, 256, 0, stream>>>(x, rawB, canonT, canonSst, resF, bufH, dflag);

  // --- cross attention ---
  tp(q_w, wT, kC, kC);
  gemm(0, bufH, wT, qB, bufCH, kBN, kC, kC, kC, kC, kC, 0, 0, 0, 1);  // qOut
  {
    long long tot = (long long)kZ * kN * kDp;
    scatter_qc<<<(int)((tot + 255) / 256), 256, 0, stream>>>(bufCH, bufQp);
  }
  tp(kv_w, wT, kC, 2 * kC);
  gemm(0, canonY, wT, kvB, kvBuf, kB * kL, 2 * kC, kC, kC, kC, 2 * kC, 0, 0, 0, 1);
  {
    long long tot = (long long)kZ * kL * kDp;
    scatter_kc<<<(int)((tot + 255) / 256), 256, 0, stream>>>(kvBuf, bufCH);  // Kc
    tot = (long long)kZ * kD * 128;
    scatter_vc<<<(int)((tot + 255) / 256), 256, 0, stream>>>(kvBuf, bufVT);  // VcT
  }
  gemm(0, bufQp, bufCH, nullptr, arena, kN, kL, kDp, kDp, kDp, 128,
       (long long)kN * kDp, (long long)kL * kDp, (long long)kN * 128, kZ);
  softmax_cross<<<kZ * kN, 128, 0, stream>>>(arena);
  gemm(0, arena, bufVT, nullptr, bufO, kN, kD, 128, 128, 128, kD,
       (long long)kN * 128, (long long)kD * 128, (long long)kN * kD, kZ);
  heads_to_cat<<<18432, 256, 0, stream>>>(bufO, bufCH);  // crossCat (Kc dead)
  tp(cproj_w, wT, kC, kC);
  gemm(0, bufCH, wT, cprojB, rawB, kBN, kC, kC, kC, kC, kC, 0, 0, 0, 1);
  resid_add<<<18432, 256, 0, stream>>>(resF, rawB);

  // --- MLP ---
  ln_mod<1><<<kBN, 256, 0, stream>>>(resF, canonT, canonSst, bufH, 3, 4, dflag);
  tp(fc1_w, wT, kC, kHid);
  tp(fc2_w, fc2T, kHid, kC);  // into dead bufQp
  gemm(2, bufH, wT, fc1B, arena, kBN, kHid, kC, kC, kC, kHid, 0, 0, 0, 1);   // w8
  gemm(0, arena, fc2T, fc2B, rawB, kBN, kC, kHid, kHid, kHid, kC, 0, 0, 0, 1);  // t64<128,64>
  final_out<<<18432, 256, 0, stream>>>(resF, rawB, canonT, canonSst, (float*)d_out);
}